// Round 6
// baseline (175.452 us; speedup 1.0000x reference)
//
#include <hip/hip_runtime.h>
#include <math.h>

constexpr int kM0 = 16, kM1 = 8, kDim = 40, kNW = 576;
constexpr int kNodes = 10000, kEdges = 160000;
constexpr int kCap = 96;  // bucket capacity; deg ~ Poisson(16), 96 >> max deg
constexpr int kNB = 24;   // nodes per k_node block (960 threads = 15 waves)

__device__ __forceinline__ float sspf(float x){
  float ax = fabsf(x);
  return fmaxf(x, 0.f) + log1pf(expf(-ax)) - 0.69314718055994531f;
}

// ---- fused: dst histogram (-> per-edge slot) + Wfc transpose + h = _lin1(x) ----
// grid exactly kEdges threads (625 * 256)
__global__ void __launch_bounds__(256) k_pre(
    const float* __restrict__ x, const float* __restrict__ W1s,
    const float* __restrict__ W1v, const float* __restrict__ Wfc,
    const int* __restrict__ edst,
    float* __restrict__ h, float* __restrict__ WfcT,
    int* __restrict__ cnt, int* __restrict__ posw){
  int t = blockIdx.x*256 + threadIdx.x;
  posw[t] = atomicAdd(&cnt[edst[t]], 1);       // t < kEdges always (exact grid)
  if (t < kNW){
    #pragma unroll
    for (int b=0;b<8;++b) WfcT[t*8+b] = Wfc[b*kNW + t];
  }
  if (t < kNodes){
    const float4* xp4 = (const float4*)(x + (size_t)t*kDim);
    float xx[40];
    #pragma unroll
    for (int i=0;i<10;++i){
      float4 v = xp4[i];
      xx[i*4]=v.x; xx[i*4+1]=v.y; xx[i*4+2]=v.z; xx[i*4+3]=v.w;
    }
    float hh[40];
    #pragma unroll
    for (int v=0; v<kM0; ++v){
      float acc = 0.f;
      #pragma unroll
      for (int u=0; u<kM0; ++u) acc += xx[u]*W1s[u*kM0+v];
      hh[v] = acc*0.25f;                       // 1/sqrt(16)
    }
    #pragma unroll
    for (int v=0; v<kM1; ++v){
      float a0=0.f,a1=0.f,a2=0.f;
      #pragma unroll
      for (int u=0; u<kM1; ++u){
        float wv = W1v[u*kM1+v];
        a0 += xx[16+u*3+0]*wv;
        a1 += xx[16+u*3+1]*wv;
        a2 += xx[16+u*3+2]*wv;
      }
      hh[16+v*3+0]=a0*0.35355339059327373f;    // 1/sqrt(8)
      hh[16+v*3+1]=a1*0.35355339059327373f;
      hh[16+v*3+2]=a2*0.35355339059327373f;
    }
    float4* hp4 = (float4*)(h + (size_t)t*kDim);
    #pragma unroll
    for (int i=0;i<10;++i)
      hp4[i] = make_float4(hh[i*4],hh[i*4+1],hh[i*4+2],hh[i*4+3]);
  }
}

// ---------------- per-edge messages: 2 threads (in 2 waves) per edge ----------------
// block = 256 thr = 4 waves -> 128 edges; wave pair q=0/1 computes w-half q.
// Wfc indices stay wave-uniform -> s_load; h preloaded into registers.
__global__ void __launch_bounds__(256) k_edge(
    const float* __restrict__ er, const float* __restrict__ esh,
    const int* __restrict__ esrc, const int* __restrict__ edst,
    const int* __restrict__ posw,
    const float* __restrict__ h, const float* __restrict__ WfcT,
    float* __restrict__ msg){
  int lane = threadIdx.x & 63;
  int wv8 = threadIdx.x >> 6;                                  // 0..3
  int q   = __builtin_amdgcn_readfirstlane(wv8 & 1);           // 0/1, wave-uniform
  int e = blockIdx.x*128 + (wv8>>1)*64 + lane;                 // exact grid: 1250*128
  float4 ra = *(const float4*)(er + (size_t)e*8);
  float4 rb = *(const float4*)(er + (size_t)e*8 + 4);
  const float r0=ra.x,r1=ra.y,r2=ra.z,r3=ra.w,r4=rb.x,r5=rb.y,r6=rb.z,r7=rb.w;
  float4 s4 = *(const float4*)(esh + (size_t)e*4);
  // ---- preload all 40 h floats as 10 independent float4 loads ----
  const float4* hv4 = (const float4*)(h + (size_t)esrc[e]*kDim);
  float hh[40];
  #pragma unroll
  for (int i=0;i<10;++i){
    float4 v = hv4[i];
    hh[i*4]=v.x; hh[i*4+1]=v.y; hh[i*4+2]=v.z; hh[i*4+3]=v.w;
  }
  float* mp = msg + ((size_t)edst[e]*kCap + posw[e])*kDim;

#define DOT8(p) ((p)[0]*r0+(p)[1]*r1+(p)[2]*r2+(p)[3]*r3+(p)[4]*r4+(p)[5]*r5+(p)[6]*r6+(p)[7]*r7)

  const int w0 = q*8;     // scalar w-range [w0, w0+8)
  const int w2 = q*4;     // vector w-range [w2, w2+4)
  float t00[8]={0,0,0,0,0,0,0,0}, t11[8]={0,0,0,0,0,0,0,0};
  float t01[4]={0,0,0,0}, tx[4]={0,0,0,0}, ty[4]={0,0,0,0}, tz[4]={0,0,0,0};

  #pragma unroll
  for (int u=0;u<16;++u){
    float xu = hh[u];
    const float* p0 = WfcT + (size_t)(u*16 + w0)*8;
    #pragma unroll
    for (int wi=0;wi<8;++wi) t00[wi] += xu*DOT8(p0 + wi*8);
    const float* p1 = WfcT + (size_t)(256 + u*8 + w2)*8;
    #pragma unroll
    for (int wi=0;wi<4;++wi) t01[wi] += xu*DOT8(p1 + wi*8);
  }
  #pragma unroll
  for (int u=0;u<8;++u){
    float v0=hh[16+u*3], v1=hh[16+u*3+1], v2=hh[16+u*3+2];
    float au = v0*s4.y + v1*s4.z + v2*s4.w;
    const float* p3 = WfcT + (size_t)(448 + u*16 + w0)*8;
    #pragma unroll
    for (int wi=0;wi<8;++wi) t11[wi] += au*DOT8(p3 + wi*8);
    const float* p2 = WfcT + (size_t)(384 + u*8 + w2)*8;
    #pragma unroll
    for (int wi=0;wi<4;++wi){
      float a = DOT8(p2 + wi*8);
      tx[wi] += v0*a; ty[wi] += v1*a; tz[wi] += v2*a;
    }
  }
#undef DOT8

  constexpr float cs00 = 0.0625f;               // inv2/(sqrt8*4)
  constexpr float cs11 = 0.05103103630798288f;  // 1/sqrt(384)
  constexpr float cv01 = 0.0625f;
  constexpr float cv10 = 0.08838834764831845f;  // inv2/8

  float ms[8];
  #pragma unroll
  for (int wi=0;wi<8;++wi) ms[wi] = s4.x*t00[wi]*cs00 + t11[wi]*cs11;
  *(float4*)(mp + w0)     = make_float4(ms[0],ms[1],ms[2],ms[3]);
  *(float4*)(mp + w0 + 4) = make_float4(ms[4],ms[5],ms[6],ms[7]);

  // vector half: 12 floats at float-offset 16 + q*12 (16,28 -> both 16B-aligned)
  float mv[12];
  float sc0 = s4.x*cv10;
  #pragma unroll
  for (int wi=0;wi<4;++wi){
    float va = t01[wi]*cv01;
    mv[wi*3+0] = s4.y*va + tx[wi]*sc0;
    mv[wi*3+1] = s4.z*va + ty[wi]*sc0;
    mv[wi*3+2] = s4.w*va + tz[wi]*sc0;
  }
  float* vp = mp + 16 + q*12;
  *(float4*)(vp+0) = make_float4(mv[0],mv[1],mv[2],mv[3]);
  *(float4*)(vp+4) = make_float4(mv[4],mv[5],mv[6],mv[7]);
  *(float4*)(vp+8) = make_float4(mv[8],mv[9],mv[10],mv[11]);
}

// ---------------- fused gather + linear2 + gate + residual, LDS-staged weights ----------------
__global__ void __launch_bounds__(960) k_node(
    const float* __restrict__ x, const float* __restrict__ msg,
    const int* __restrict__ cnt,
    const float* __restrict__ W2s, const float* __restrict__ W2v,
    const float* __restrict__ R00, const float* __restrict__ R01,
    const float* __restrict__ R10, const float* __restrict__ R11,
    float* __restrict__ out){
  __shared__ float sR00[4096], sR01[1024], sR10[1024], sR11[1024];
  __shared__ float sW2s[256], sW2v[64];
  __shared__ float sx[kNB][40], sa[kNB][40];
  int t = threadIdx.x;
  // ---- stage weights (float4, coalesced) ----
  for (int i=t; i<1024; i+=960) ((float4*)sR00)[i] = ((const float4*)R00)[i];
  if (t < 256){
    ((float4*)sR01)[t] = ((const float4*)R01)[t];
    ((float4*)sR10)[t] = ((const float4*)R10)[t];
    ((float4*)sR11)[t] = ((const float4*)R11)[t];
  }
  if (t < 64) ((float4*)sW2s)[t] = ((const float4*)W2s)[t];
  if (t < 16) ((float4*)sW2v)[t] = ((const float4*)W2v)[t];
  // ---- gather from bucket (4 independent accumulators for MLP) ----
  int nb = blockIdx.x*kNB;
  {
    int ns = t/40, c = t - ns*40, n = nb + ns;
    float a0=0.f,a1=0.f,a2=0.f,a3=0.f, xval=0.f;
    if (n < kNodes){
      int deg = cnt[n];
      const float* bp = msg + (size_t)n*kCap*kDim + c;
      int k=0;
      for (; k+4<=deg; k+=4){
        a0 += bp[(size_t)(k+0)*kDim];
        a1 += bp[(size_t)(k+1)*kDim];
        a2 += bp[(size_t)(k+2)*kDim];
        a3 += bp[(size_t)(k+3)*kDim];
      }
      for (; k<deg; ++k) a0 += bp[(size_t)k*kDim];
      xval = x[(size_t)n*kDim + c];
    }
    sa[ns][c] = ((a0+a1)+(a2+a3))*0.25f;     // fold 1/deg = 1/4
    sx[ns][c] = xval;
  }
  __syncthreads();
  if (t < kNB*16){
    // ---- scalar outputs ----
    int ns = t>>4, w = t&15, n = nb+ns;
    const float* ap = sa[ns];
    const float* xp = sx[ns];
    float hsum = 0.f;
    #pragma unroll
    for (int u=0;u<16;++u) hsum += ap[u]*sW2s[u*16+w];
    hsum *= 0.25f;                 // 1/sqrt(16)
    float nrm = sqrtf(hsum*hsum + 1e-16f);
    float val = hsum/nrm*sspf(nrm);
    float xs[16];
    #pragma unroll
    for (int v=0;v<16;++v) xs[v] = xp[v];
    float r0 = 0.f;
    #pragma unroll
    for (int u=0;u<16;++u){
      float tacc = 0.f;
      #pragma unroll
      for (int v=0;v<16;++v) tacc += xs[v]*sR00[(u*16+v)*16+w];
      r0 += xs[u]*tacc;
    }
    float xv[24];
    #pragma unroll
    for (int c2=0;c2<24;++c2) xv[c2] = xp[16+c2];
    float r1 = 0.f;
    #pragma unroll
    for (int u=0;u<8;++u){
      #pragma unroll
      for (int v=0;v<8;++v){
        float dot = xv[u*3]*xv[v*3] + xv[u*3+1]*xv[v*3+1] + xv[u*3+2]*xv[v*3+2];
        r1 += dot*sR11[(u*8+v)*16+w];
      }
    }
    if (n < kNodes)
      out[(size_t)n*kDim + w] = val + 0.04419417382415922f*r0 + 0.05103103630798288f*r1;
  } else {
    // ---- vector outputs ----
    int t2 = t - kNB*16;
    int ns = t2/24, cc = t2 - ns*24, w = cc/3, i = cc - w*3, n = nb+ns;
    const float* ap = sa[ns] + 16;
    const float* xp = sx[ns];
    float h0=0.f,h1=0.f,h2=0.f;
    #pragma unroll
    for (int u=0;u<8;++u){
      float wv = sW2v[u*8+w];
      h0 += ap[u*3+0]*wv; h1 += ap[u*3+1]*wv; h2 += ap[u*3+2]*wv;
    }
    const float sc = 0.35355339059327373f;   // 1/sqrt(8)
    h0*=sc; h1*=sc; h2*=sc;
    float nv = sqrtf(h0*h0+h1*h1+h2*h2 + 1e-16f);
    float hi = (i==0)?h0:((i==1)?h1:h2);
    float val = hi/nv*sspf(nv);
    float xs[16];
    #pragma unroll
    for (int v=0;v<16;++v) xs[v] = xp[v];
    float xvi[8];
    #pragma unroll
    for (int v=0;v<8;++v) xvi[v] = xp[16+v*3+i];
    float racc = 0.f;
    #pragma unroll
    for (int u=0;u<16;++u){
      float tacc=0.f;
      #pragma unroll
      for (int v=0;v<8;++v) tacc += xvi[v]*sR01[(u*8+v)*8+w];
      racc += xs[u]*tacc;
    }
    #pragma unroll
    for (int u=0;u<8;++u){
      float tacc=0.f;
      #pragma unroll
      for (int v=0;v<16;++v) tacc += xs[v]*sR10[(u*16+v)*8+w];
      racc += xvi[u]*tacc;
    }
    if (n < kNodes)
      out[(size_t)n*kDim + 16 + cc] = val + 0.0625f*racc;   // inv2/sqrt(128)
  }
}

extern "C" void kernel_launch(void* const* d_in, const int* in_sizes, int n_in,
                              void* d_out, int out_size, void* d_ws, size_t ws_size,
                              hipStream_t stream){
  const float* x   = (const float*)d_in[0];
  const float* er  = (const float*)d_in[1];
  const float* esh = (const float*)d_in[2];
  const int*   esrc= (const int*)d_in[3];
  const int*   edst= (const int*)d_in[4];
  const float* W1s = (const float*)d_in[6];
  const float* W1v = (const float*)d_in[7];
  const float* Wfc = (const float*)d_in[8];
  const float* W2s = (const float*)d_in[9];
  const float* W2v = (const float*)d_in[10];
  const float* R00 = (const float*)d_in[11];
  const float* R01 = (const float*)d_in[12];
  const float* R10 = (const float*)d_in[13];
  const float* R11 = (const float*)d_in[14];
  float* out = (float*)d_out;

  // ws layout (16B-aligned blocks)
  char* wsb = (char*)d_ws;
  float* h    = (float*)wsb;                                     // 400,000 f (1.6 MB)
  float* msg  = h + (size_t)kNodes*kDim;                         // 10000*96*40 f (153.6 MB)
  float* WfcT = msg + (size_t)kNodes*kCap*kDim;                  // 4,608 f
  int*   cnt  = (int*)(WfcT + (size_t)kNW*8);                    // 10,000
  int*   posw = cnt + kNodes;                                    // 160,000

  hipMemsetAsync(cnt, 0, kNodes*sizeof(int), stream);
  k_pre<<<kEdges/256, 256, 0, stream>>>(x, W1s, W1v, Wfc, edst, h, WfcT, cnt, posw);
  k_edge<<<kEdges/128, 256, 0, stream>>>(er, esh, esrc, edst, posw, h, WfcT, msg);
  k_node<<<(kNodes+kNB-1)/kNB, 960, 0, stream>>>(x, msg, cnt, W2s, W2v, R00, R01, R10, R11, out);
}

// Round 7
// 158.517 us; speedup vs baseline: 1.1068x; 1.1068x over previous
//
#include <hip/hip_runtime.h>
#include <math.h>

constexpr int kM0 = 16, kM1 = 8, kDim = 40, kNW = 576;
constexpr int kNodes = 10000, kEdges = 160000;
constexpr int kCap = 96;  // bucket capacity; deg ~ Poisson(16), 96 >> max deg
constexpr int kNB = 24;   // nodes per k_node block (960 threads = 15 waves)

__device__ __forceinline__ float sspf(float x){
  float ax = fabsf(x);
  return fmaxf(x, 0.f) + log1pf(expf(-ax)) - 0.69314718055994531f;
}

// ---- fused: dst histogram (-> per-edge slot) + Wfc transpose + h = _lin1(x) ----
// grid exactly kEdges threads (625 * 256)
__global__ void __launch_bounds__(256) k_pre(
    const float* __restrict__ x, const float* __restrict__ W1s,
    const float* __restrict__ W1v, const float* __restrict__ Wfc,
    const int* __restrict__ edst,
    float* __restrict__ h, float* __restrict__ WfcT,
    int* __restrict__ cnt, int* __restrict__ posw){
  int t = blockIdx.x*256 + threadIdx.x;
  posw[t] = atomicAdd(&cnt[edst[t]], 1);       // t < kEdges always (exact grid)
  if (t < kNW){
    #pragma unroll
    for (int b=0;b<8;++b) WfcT[t*8+b] = Wfc[b*kNW + t];
  }
  if (t < kNodes){
    const float4* xp4 = (const float4*)(x + (size_t)t*kDim);
    float xx[40];
    #pragma unroll
    for (int i=0;i<10;++i){
      float4 v = xp4[i];
      xx[i*4]=v.x; xx[i*4+1]=v.y; xx[i*4+2]=v.z; xx[i*4+3]=v.w;
    }
    float hh[40];
    #pragma unroll
    for (int v=0; v<kM0; ++v){
      float acc = 0.f;
      #pragma unroll
      for (int u=0; u<kM0; ++u) acc += xx[u]*W1s[u*kM0+v];
      hh[v] = acc*0.25f;                       // 1/sqrt(16)
    }
    #pragma unroll
    for (int v=0; v<kM1; ++v){
      float a0=0.f,a1=0.f,a2=0.f;
      #pragma unroll
      for (int u=0; u<kM1; ++u){
        float wv = W1v[u*kM1+v];
        a0 += xx[16+u*3+0]*wv;
        a1 += xx[16+u*3+1]*wv;
        a2 += xx[16+u*3+2]*wv;
      }
      hh[16+v*3+0]=a0*0.35355339059327373f;    // 1/sqrt(8)
      hh[16+v*3+1]=a1*0.35355339059327373f;
      hh[16+v*3+2]=a2*0.35355339059327373f;
    }
    float4* hp4 = (float4*)(h + (size_t)t*kDim);
    #pragma unroll
    for (int i=0;i<10;++i)
      hp4[i] = make_float4(hh[i*4],hh[i*4+1],hh[i*4+2],hh[i*4+3]);
  }
}

// ---------------- per-edge messages: 8 waves per 64-edge group ----------------
// block = 512 thr = 8 waves; all waves cover the SAME 64 edges, wave q owns
// w-slice q (2 scalar w, 1 vector w). WfcT addresses are wave-uniform -> s_load.
__global__ void __launch_bounds__(512) k_edge(
    const float* __restrict__ er, const float* __restrict__ esh,
    const int* __restrict__ esrc, const int* __restrict__ edst,
    const int* __restrict__ posw,
    const float* __restrict__ h, const float* __restrict__ WfcT,
    float* __restrict__ msg){
  int lane = threadIdx.x & 63;
  int q = __builtin_amdgcn_readfirstlane(threadIdx.x >> 6);   // 0..7, wave-uniform
  int e = blockIdx.x*64 + lane;                               // exact grid: 2500*64
  float4 ra = *(const float4*)(er + (size_t)e*8);
  float4 rb = *(const float4*)(er + (size_t)e*8 + 4);
  const float r0=ra.x,r1=ra.y,r2=ra.z,r3=ra.w,r4=rb.x,r5=rb.y,r6=rb.z,r7=rb.w;
  float4 s4 = *(const float4*)(esh + (size_t)e*4);
  const float* hp = h + (size_t)esrc[e]*kDim;
  float* mp = msg + ((size_t)edst[e]*kCap + posw[e])*kDim;

#define DOT8(p) ((p)[0]*r0+(p)[1]*r1+(p)[2]*r2+(p)[3]*r3+(p)[4]*r4+(p)[5]*r5+(p)[6]*r6+(p)[7]*r7)

  const int w0 = q*2;     // scalar w-range [w0, w0+2)
  // vector w index = q
  float t00a=0.f, t00b=0.f, t11a=0.f, t11b=0.f;
  float t01=0.f, tx=0.f, ty=0.f, tz=0.f;

  #pragma unroll
  for (int u=0;u<16;++u){
    float xu = hp[u];
    const float* p0 = WfcT + (size_t)(u*16 + w0)*8;
    t00a += xu*DOT8(p0);
    t00b += xu*DOT8(p0 + 8);
    const float* p1 = WfcT + (size_t)(256 + u*8 + q)*8;
    t01 += xu*DOT8(p1);
  }
  #pragma unroll
  for (int u=0;u<8;++u){
    float v0=hp[16+u*3], v1=hp[16+u*3+1], v2=hp[16+u*3+2];
    float au = v0*s4.y + v1*s4.z + v2*s4.w;
    const float* p3 = WfcT + (size_t)(448 + u*16 + w0)*8;
    t11a += au*DOT8(p3);
    t11b += au*DOT8(p3 + 8);
    const float* p2 = WfcT + (size_t)(384 + u*8 + q)*8;
    float a = DOT8(p2);
    tx += v0*a; ty += v1*a; tz += v2*a;
  }
#undef DOT8

  constexpr float cs00 = 0.0625f;               // inv2/(sqrt8*4)
  constexpr float cs11 = 0.05103103630798288f;  // 1/sqrt(384)
  constexpr float cv01 = 0.0625f;
  constexpr float cv10 = 0.08838834764831845f;  // inv2/8

  // scalar pair at mp + 2q (8B-aligned)
  *(float2*)(mp + w0) = make_float2(s4.x*t00a*cs00 + t11a*cs11,
                                    s4.x*t00b*cs00 + t11b*cs11);
  // vector triple at mp + 16 + 3q (4B-aligned -> scalar stores)
  float va = t01*cv01, sc0 = s4.x*cv10;
  float* vp = mp + 16 + q*3;
  vp[0] = s4.y*va + tx*sc0;
  vp[1] = s4.z*va + ty*sc0;
  vp[2] = s4.w*va + tz*sc0;
}

// ---------------- fused gather + linear2 + gate + residual, LDS-staged weights ----------------
__global__ void __launch_bounds__(960) k_node(
    const float* __restrict__ x, const float* __restrict__ msg,
    const int* __restrict__ cnt,
    const float* __restrict__ W2s, const float* __restrict__ W2v,
    const float* __restrict__ R00, const float* __restrict__ R01,
    const float* __restrict__ R10, const float* __restrict__ R11,
    float* __restrict__ out){
  __shared__ float sR00[4096], sR01[1024], sR10[1024], sR11[1024];
  __shared__ float sW2s[256], sW2v[64];
  __shared__ float sx[kNB][40], sa[kNB][40];
  int t = threadIdx.x;
  // ---- stage weights (float4, coalesced) ----
  for (int i=t; i<1024; i+=960) ((float4*)sR00)[i] = ((const float4*)R00)[i];
  if (t < 256){
    ((float4*)sR01)[t] = ((const float4*)R01)[t];
    ((float4*)sR10)[t] = ((const float4*)R10)[t];
    ((float4*)sR11)[t] = ((const float4*)R11)[t];
  }
  if (t < 64) ((float4*)sW2s)[t] = ((const float4*)W2s)[t];
  if (t < 16) ((float4*)sW2v)[t] = ((const float4*)W2v)[t];
  // ---- gather from bucket (4 independent accumulators) ----
  int nb = blockIdx.x*kNB;
  {
    int ns = t/40, c = t - ns*40, n = nb + ns;
    float a0=0.f,a1=0.f,a2=0.f,a3=0.f, xval=0.f;
    if (n < kNodes){
      int deg = cnt[n];
      const float* bp = msg + (size_t)n*kCap*kDim + c;
      int k=0;
      for (; k+4<=deg; k+=4){
        a0 += bp[(size_t)(k+0)*kDim];
        a1 += bp[(size_t)(k+1)*kDim];
        a2 += bp[(size_t)(k+2)*kDim];
        a3 += bp[(size_t)(k+3)*kDim];
      }
      for (; k<deg; ++k) a0 += bp[(size_t)k*kDim];
      xval = x[(size_t)n*kDim + c];
    }
    sa[ns][c] = ((a0+a1)+(a2+a3))*0.25f;     // fold 1/deg = 1/4
    sx[ns][c] = xval;
  }
  __syncthreads();
  if (t < kNB*16){
    // ---- scalar outputs ----
    int ns = t>>4, w = t&15, n = nb+ns;
    const float* ap = sa[ns];
    const float* xp = sx[ns];
    float hsum = 0.f;
    #pragma unroll
    for (int u=0;u<16;++u) hsum += ap[u]*sW2s[u*16+w];
    hsum *= 0.25f;                 // 1/sqrt(16)
    float nrm = sqrtf(hsum*hsum + 1e-16f);
    float val = hsum/nrm*sspf(nrm);
    float xs[16];
    #pragma unroll
    for (int v=0;v<16;++v) xs[v] = xp[v];
    float r0 = 0.f;
    #pragma unroll
    for (int u=0;u<16;++u){
      float tacc = 0.f;
      #pragma unroll
      for (int v=0;v<16;++v) tacc += xs[v]*sR00[(u*16+v)*16+w];
      r0 += xs[u]*tacc;
    }
    float xv[24];
    #pragma unroll
    for (int c2=0;c2<24;++c2) xv[c2] = xp[16+c2];
    float r1 = 0.f;
    #pragma unroll
    for (int u=0;u<8;++u){
      #pragma unroll
      for (int v=0;v<8;++v){
        float dot = xv[u*3]*xv[v*3] + xv[u*3+1]*xv[v*3+1] + xv[u*3+2]*xv[v*3+2];
        r1 += dot*sR11[(u*8+v)*16+w];
      }
    }
    if (n < kNodes)
      out[(size_t)n*kDim + w] = val + 0.04419417382415922f*r0 + 0.05103103630798288f*r1;
  } else {
    // ---- vector outputs ----
    int t2 = t - kNB*16;
    int ns = t2/24, cc = t2 - ns*24, w = cc/3, i = cc - w*3, n = nb+ns;
    const float* ap = sa[ns] + 16;
    const float* xp = sx[ns];
    float h0=0.f,h1=0.f,h2=0.f;
    #pragma unroll
    for (int u=0;u<8;++u){
      float wv = sW2v[u*8+w];
      h0 += ap[u*3+0]*wv; h1 += ap[u*3+1]*wv; h2 += ap[u*3+2]*wv;
    }
    const float sc = 0.35355339059327373f;   // 1/sqrt(8)
    h0*=sc; h1*=sc; h2*=sc;
    float nv = sqrtf(h0*h0+h1*h1+h2*h2 + 1e-16f);
    float hi = (i==0)?h0:((i==1)?h1:h2);
    float val = hi/nv*sspf(nv);
    float xs[16];
    #pragma unroll
    for (int v=0;v<16;++v) xs[v] = xp[v];
    float xvi[8];
    #pragma unroll
    for (int v=0;v<8;++v) xvi[v] = xp[16+v*3+i];
    float racc = 0.f;
    #pragma unroll
    for (int u=0;u<16;++u){
      float tacc=0.f;
      #pragma unroll
      for (int v=0;v<8;++v) tacc += xvi[v]*sR01[(u*8+v)*8+w];
      racc += xs[u]*tacc;
    }
    #pragma unroll
    for (int u=0;u<8;++u){
      float tacc=0.f;
      #pragma unroll
      for (int v=0;v<16;++v) tacc += xs[v]*sR10[(u*16+v)*8+w];
      racc += xvi[u]*tacc;
    }
    if (n < kNodes)
      out[(size_t)n*kDim + 16 + cc] = val + 0.0625f*racc;   // inv2/sqrt(128)
  }
}

extern "C" void kernel_launch(void* const* d_in, const int* in_sizes, int n_in,
                              void* d_out, int out_size, void* d_ws, size_t ws_size,
                              hipStream_t stream){
  const float* x   = (const float*)d_in[0];
  const float* er  = (const float*)d_in[1];
  const float* esh = (const float*)d_in[2];
  const int*   esrc= (const int*)d_in[3];
  const int*   edst= (const int*)d_in[4];
  const float* W1s = (const float*)d_in[6];
  const float* W1v = (const float*)d_in[7];
  const float* Wfc = (const float*)d_in[8];
  const float* W2s = (const float*)d_in[9];
  const float* W2v = (const float*)d_in[10];
  const float* R00 = (const float*)d_in[11];
  const float* R01 = (const float*)d_in[12];
  const float* R10 = (const float*)d_in[13];
  const float* R11 = (const float*)d_in[14];
  float* out = (float*)d_out;

  // ws layout (16B-aligned blocks)
  char* wsb = (char*)d_ws;
  float* h    = (float*)wsb;                                     // 400,000 f (1.6 MB)
  float* msg  = h + (size_t)kNodes*kDim;                         // 10000*96*40 f (153.6 MB)
  float* WfcT = msg + (size_t)kNodes*kCap*kDim;                  // 4,608 f
  int*   cnt  = (int*)(WfcT + (size_t)kNW*8);                    // 10,000
  int*   posw = cnt + kNodes;                                    // 160,000

  hipMemsetAsync(cnt, 0, kNodes*sizeof(int), stream);
  k_pre<<<kEdges/256, 256, 0, stream>>>(x, W1s, W1v, Wfc, edst, h, WfcT, cnt, posw);
  k_edge<<<kEdges/64, 512, 0, stream>>>(er, esh, esrc, edst, posw, h, WfcT, msg);
  k_node<<<(kNodes+kNB-1)/kNB, 960, 0, stream>>>(x, msg, cnt, W2s, W2v, R00, R01, R10, R11, out);
}

// Round 8
// 155.072 us; speedup vs baseline: 1.1314x; 1.0222x over previous
//
#include <hip/hip_runtime.h>
#include <math.h>

constexpr int kM0 = 16, kM1 = 8, kDim = 40, kNW = 576;
constexpr int kNodes = 10000, kEdges = 160000;
constexpr int kCap = 96;  // bucket capacity; deg ~ Poisson(16), 96 >> max deg
constexpr int kNB = 24;   // nodes per k_node block (960 threads = 15 waves)

__device__ __forceinline__ float sspf(float x){
  float ax = fabsf(x);
  return fmaxf(x, 0.f) + log1pf(expf(-ax)) - 0.69314718055994531f;
}

// ---- fused: dst histogram (-> per-edge slot) + Wfc transpose + h = _lin1(x) ----
// grid exactly kEdges threads (625 * 256)
__global__ void __launch_bounds__(256) k_pre(
    const float* __restrict__ x, const float* __restrict__ W1s,
    const float* __restrict__ W1v, const float* __restrict__ Wfc,
    const int* __restrict__ edst,
    float* __restrict__ h, float* __restrict__ WfcT,
    int* __restrict__ cnt, int* __restrict__ posw){
  int t = blockIdx.x*256 + threadIdx.x;
  posw[t] = atomicAdd(&cnt[edst[t]], 1);       // t < kEdges always (exact grid)
  if (t < kNW){
    #pragma unroll
    for (int b=0;b<8;++b) WfcT[t*8+b] = Wfc[b*kNW + t];
  }
  if (t < kNodes){
    const float4* xp4 = (const float4*)(x + (size_t)t*kDim);
    float xx[40];
    #pragma unroll
    for (int i=0;i<10;++i){
      float4 v = xp4[i];
      xx[i*4]=v.x; xx[i*4+1]=v.y; xx[i*4+2]=v.z; xx[i*4+3]=v.w;
    }
    float hh[40];
    #pragma unroll
    for (int v=0; v<kM0; ++v){
      float acc = 0.f;
      #pragma unroll
      for (int u=0; u<kM0; ++u) acc += xx[u]*W1s[u*kM0+v];
      hh[v] = acc*0.25f;                       // 1/sqrt(16)
    }
    #pragma unroll
    for (int v=0; v<kM1; ++v){
      float a0=0.f,a1=0.f,a2=0.f;
      #pragma unroll
      for (int u=0; u<kM1; ++u){
        float wv = W1v[u*kM1+v];
        a0 += xx[16+u*3+0]*wv;
        a1 += xx[16+u*3+1]*wv;
        a2 += xx[16+u*3+2]*wv;
      }
      hh[16+v*3+0]=a0*0.35355339059327373f;    // 1/sqrt(8)
      hh[16+v*3+1]=a1*0.35355339059327373f;
      hh[16+v*3+2]=a2*0.35355339059327373f;
    }
    float4* hp4 = (float4*)(h + (size_t)t*kDim);
    #pragma unroll
    for (int i=0;i<10;++i)
      hp4[i] = make_float4(hh[i*4],hh[i*4+1],hh[i*4+2],hh[i*4+3]);
  }
}

// ---------------- per-edge messages: 8 waves per 64-edge group ----------------
// block = 512 thr = 8 waves; all waves cover the SAME 64 edges, wave q owns
// w-slice q (2 scalar w, 1 vector w). WfcT addresses wave-uniform -> s_load.
// h rows for the 64 edges staged ONCE in LDS (pad 41: stride mod 32 = 9,
// coprime with 32 -> 2 lanes/bank = conflict-free).
__global__ void __launch_bounds__(512) k_edge(
    const float* __restrict__ er, const float* __restrict__ esh,
    const int* __restrict__ esrc, const int* __restrict__ edst,
    const int* __restrict__ posw,
    const float* __restrict__ h, const float* __restrict__ WfcT,
    float* __restrict__ msg){
  __shared__ float sh_h[64][41];
  int t = threadIdx.x;
  int e0 = blockIdx.x*64;                      // exact grid: 2500*64
  // ---- cooperative stage: 64 edges x 10 float4 = 640 chunks ----
  for (int idx = t; idx < 640; idx += 512){
    int el = idx/10, c4 = idx - el*10;
    int src = esrc[e0 + el];
    const float4 v = *(const float4*)(h + (size_t)src*kDim + c4*4);
    float* d = &sh_h[el][c4*4];
    d[0]=v.x; d[1]=v.y; d[2]=v.z; d[3]=v.w;
  }
  __syncthreads();

  int lane = t & 63;
  int q = __builtin_amdgcn_readfirstlane(t >> 6);   // 0..7, wave-uniform
  int e = e0 + lane;
  float4 ra = *(const float4*)(er + (size_t)e*8);
  float4 rb = *(const float4*)(er + (size_t)e*8 + 4);
  const float r0=ra.x,r1=ra.y,r2=ra.z,r3=ra.w,r4=rb.x,r5=rb.y,r6=rb.z,r7=rb.w;
  float4 s4 = *(const float4*)(esh + (size_t)e*4);
  const float* hl = sh_h[lane];
  float* mp = msg + ((size_t)edst[e]*kCap + posw[e])*kDim;

#define DOT8(p) ((p)[0]*r0+(p)[1]*r1+(p)[2]*r2+(p)[3]*r3+(p)[4]*r4+(p)[5]*r5+(p)[6]*r6+(p)[7]*r7)

  const int w0 = q*2;     // scalar w-range [w0, w0+2)
  // vector w index = q
  float t00a=0.f, t00b=0.f, t11a=0.f, t11b=0.f;
  float t01=0.f, tx=0.f, ty=0.f, tz=0.f;

  #pragma unroll
  for (int u=0;u<16;++u){
    float xu = hl[u];
    const float* p0 = WfcT + (size_t)(u*16 + w0)*8;
    t00a += xu*DOT8(p0);
    t00b += xu*DOT8(p0 + 8);
    const float* p1 = WfcT + (size_t)(256 + u*8 + q)*8;
    t01 += xu*DOT8(p1);
  }
  #pragma unroll
  for (int u=0;u<8;++u){
    float v0=hl[16+u*3], v1=hl[16+u*3+1], v2=hl[16+u*3+2];
    float au = v0*s4.y + v1*s4.z + v2*s4.w;
    const float* p3 = WfcT + (size_t)(448 + u*16 + w0)*8;
    t11a += au*DOT8(p3);
    t11b += au*DOT8(p3 + 8);
    const float* p2 = WfcT + (size_t)(384 + u*8 + q)*8;
    float a = DOT8(p2);
    tx += v0*a; ty += v1*a; tz += v2*a;
  }
#undef DOT8

  constexpr float cs00 = 0.0625f;               // inv2/(sqrt8*4)
  constexpr float cs11 = 0.05103103630798288f;  // 1/sqrt(384)
  constexpr float cv01 = 0.0625f;
  constexpr float cv10 = 0.08838834764831845f;  // inv2/8

  // scalar pair at mp + 2q (8B-aligned)
  *(float2*)(mp + w0) = make_float2(s4.x*t00a*cs00 + t11a*cs11,
                                    s4.x*t00b*cs00 + t11b*cs11);
  // vector triple at mp + 16 + 3q (4B-aligned -> scalar stores)
  float va = t01*cv01, sc0 = s4.x*cv10;
  float* vp = mp + 16 + q*3;
  vp[0] = s4.y*va + tx*sc0;
  vp[1] = s4.z*va + ty*sc0;
  vp[2] = s4.w*va + tz*sc0;
}

// ---------------- fused gather + linear2 + gate + residual, LDS-staged weights ----------------
// 960 threads = 24 nodes; gather mapping t -> (node, float4-chunk, k-phase) = 24*10*4.
__global__ void __launch_bounds__(960) k_node(
    const float* __restrict__ x, const float* __restrict__ msg,
    const int* __restrict__ cnt,
    const float* __restrict__ W2s, const float* __restrict__ W2v,
    const float* __restrict__ R00, const float* __restrict__ R01,
    const float* __restrict__ R10, const float* __restrict__ R11,
    float* __restrict__ out){
  __shared__ float sR00[4096], sR01[1024], sR10[1024], sR11[1024];
  __shared__ float sW2s[256], sW2v[64];
  __shared__ float sx[kNB][40], sa[kNB][40];
  __shared__ float4 sred[kNB][4][10];
  int t = threadIdx.x;
  // ---- stage weights (float4, coalesced) ----
  for (int i=t; i<1024; i+=960) ((float4*)sR00)[i] = ((const float4*)R00)[i];
  if (t < 256){
    ((float4*)sR01)[t] = ((const float4*)R01)[t];
    ((float4*)sR10)[t] = ((const float4*)R10)[t];
    ((float4*)sR11)[t] = ((const float4*)R11)[t];
  }
  if (t >= 256 && t < 320) ((float4*)sW2s)[t-256] = ((const float4*)W2s)[t-256];
  if (t >= 320 && t < 336) ((float4*)sW2v)[t-320] = ((const float4*)W2v)[t-320];
  // ---- gather from bucket: vectorized, 4 k-phases ----
  int nb = blockIdx.x*kNB;
  {
    int ns = t/40; int rem = t - ns*40; int kq = rem/10; int c4 = rem - kq*10;
    int n = nb + ns;
    float4 acc = make_float4(0.f,0.f,0.f,0.f);
    if (n < kNodes){
      int deg = cnt[n];
      const float* bp = msg + (size_t)n*kCap*kDim + c4*4;
      for (int k=kq; k<deg; k+=4){
        const float4 v = *(const float4*)(bp + (size_t)k*kDim);
        acc.x+=v.x; acc.y+=v.y; acc.z+=v.z; acc.w+=v.w;
      }
    }
    sred[ns][kq][c4] = acc;
  }
  __syncthreads();
  if (t < kNB*10){
    int ns = t/10, c4 = t - ns*10, n = nb+ns;
    float4 a0 = sred[ns][0][c4], a1 = sred[ns][1][c4];
    float4 a2 = sred[ns][2][c4], a3 = sred[ns][3][c4];
    sa[ns][c4*4+0] = (a0.x+a1.x+a2.x+a3.x)*0.25f;   // fold 1/deg = 1/4
    sa[ns][c4*4+1] = (a0.y+a1.y+a2.y+a3.y)*0.25f;
    sa[ns][c4*4+2] = (a0.z+a1.z+a2.z+a3.z)*0.25f;
    sa[ns][c4*4+3] = (a0.w+a1.w+a2.w+a3.w)*0.25f;
    float4 xv = (n < kNodes) ? *(const float4*)(x + (size_t)n*kDim + c4*4)
                             : make_float4(0.f,0.f,0.f,0.f);
    sx[ns][c4*4+0]=xv.x; sx[ns][c4*4+1]=xv.y; sx[ns][c4*4+2]=xv.z; sx[ns][c4*4+3]=xv.w;
  }
  __syncthreads();
  if (t < kNB*16){
    // ---- scalar outputs ----
    int ns = t>>4, w = t&15, n = nb+ns;
    const float* ap = sa[ns];
    const float* xp = sx[ns];
    float hsum = 0.f;
    #pragma unroll
    for (int u=0;u<16;++u) hsum += ap[u]*sW2s[u*16+w];
    hsum *= 0.25f;                 // 1/sqrt(16)
    float nrm = sqrtf(hsum*hsum + 1e-16f);
    float val = hsum/nrm*sspf(nrm);
    float xs[16];
    #pragma unroll
    for (int v=0;v<16;++v) xs[v] = xp[v];
    float r0 = 0.f;
    #pragma unroll
    for (int u=0;u<16;++u){
      float tacc = 0.f;
      #pragma unroll
      for (int v=0;v<16;++v) tacc += xs[v]*sR00[(u*16+v)*16+w];
      r0 += xs[u]*tacc;
    }
    float xv[24];
    #pragma unroll
    for (int c2=0;c2<24;++c2) xv[c2] = xp[16+c2];
    float r1 = 0.f;
    #pragma unroll
    for (int u=0;u<8;++u){
      #pragma unroll
      for (int v=0;v<8;++v){
        float dot = xv[u*3]*xv[v*3] + xv[u*3+1]*xv[v*3+1] + xv[u*3+2]*xv[v*3+2];
        r1 += dot*sR11[(u*8+v)*16+w];
      }
    }
    if (n < kNodes)
      out[(size_t)n*kDim + w] = val + 0.04419417382415922f*r0 + 0.05103103630798288f*r1;
  } else if (t >= kNB*16 && t < kNB*16 + kNB*24) {
    // ---- vector outputs ----
    int t2 = t - kNB*16;
    int ns = t2/24, cc = t2 - ns*24, w = cc/3, i = cc - w*3, n = nb+ns;
    const float* ap = sa[ns] + 16;
    const float* xp = sx[ns];
    float h0=0.f,h1=0.f,h2=0.f;
    #pragma unroll
    for (int u=0;u<8;++u){
      float wv = sW2v[u*8+w];
      h0 += ap[u*3+0]*wv; h1 += ap[u*3+1]*wv; h2 += ap[u*3+2]*wv;
    }
    const float sc = 0.35355339059327373f;   // 1/sqrt(8)
    h0*=sc; h1*=sc; h2*=sc;
    float nv = sqrtf(h0*h0+h1*h1+h2*h2 + 1e-16f);
    float hi = (i==0)?h0:((i==1)?h1:h2);
    float val = hi/nv*sspf(nv);
    float xs[16];
    #pragma unroll
    for (int v=0;v<16;++v) xs[v] = xp[v];
    float xvi[8];
    #pragma unroll
    for (int v=0;v<8;++v) xvi[v] = xp[16+v*3+i];
    float racc = 0.f;
    #pragma unroll
    for (int u=0;u<16;++u){
      float tacc=0.f;
      #pragma unroll
      for (int v=0;v<8;++v) tacc += xvi[v]*sR01[(u*8+v)*8+w];
      racc += xs[u]*tacc;
    }
    #pragma unroll
    for (int u=0;u<8;++u){
      float tacc=0.f;
      #pragma unroll
      for (int v=0;v<16;++v) tacc += xs[v]*sR10[(u*16+v)*8+w];
      racc += xvi[u]*tacc;
    }
    if (n < kNodes)
      out[(size_t)n*kDim + 16 + cc] = val + 0.0625f*racc;   // inv2/sqrt(128)
  }
}

extern "C" void kernel_launch(void* const* d_in, const int* in_sizes, int n_in,
                              void* d_out, int out_size, void* d_ws, size_t ws_size,
                              hipStream_t stream){
  const float* x   = (const float*)d_in[0];
  const float* er  = (const float*)d_in[1];
  const float* esh = (const float*)d_in[2];
  const int*   esrc= (const int*)d_in[3];
  const int*   edst= (const int*)d_in[4];
  const float* W1s = (const float*)d_in[6];
  const float* W1v = (const float*)d_in[7];
  const float* Wfc = (const float*)d_in[8];
  const float* W2s = (const float*)d_in[9];
  const float* W2v = (const float*)d_in[10];
  const float* R00 = (const float*)d_in[11];
  const float* R01 = (const float*)d_in[12];
  const float* R10 = (const float*)d_in[13];
  const float* R11 = (const float*)d_in[14];
  float* out = (float*)d_out;

  // ws layout (16B-aligned blocks)
  char* wsb = (char*)d_ws;
  float* h    = (float*)wsb;                                     // 400,000 f (1.6 MB)
  float* msg  = h + (size_t)kNodes*kDim;                         // 10000*96*40 f (153.6 MB)
  float* WfcT = msg + (size_t)kNodes*kCap*kDim;                  // 4,608 f
  int*   cnt  = (int*)(WfcT + (size_t)kNW*8);                    // 10,000
  int*   posw = cnt + kNodes;                                    // 160,000

  hipMemsetAsync(cnt, 0, kNodes*sizeof(int), stream);
  k_pre<<<kEdges/256, 256, 0, stream>>>(x, W1s, W1v, Wfc, edst, h, WfcT, cnt, posw);
  k_edge<<<kEdges/64, 512, 0, stream>>>(er, esh, esrc, edst, posw, h, WfcT, msg);
  k_node<<<(kNodes+kNB-1)/kNB, 960, 0, stream>>>(x, msg, cnt, W2s, W2v, R00, R01, R10, R11, out);
}

// Round 9
// 149.710 us; speedup vs baseline: 1.1719x; 1.0358x over previous
//
#include <hip/hip_runtime.h>
#include <math.h>

constexpr int kM0 = 16, kM1 = 8, kDim = 40, kNW = 576;
constexpr int kNodes = 10000, kEdges = 160000;
constexpr int kCap = 96;  // bucket capacity; deg ~ Poisson(16), max deg << 96
constexpr int kNB = 24;   // nodes per k_node block (960 threads = 15 waves)

__device__ __forceinline__ float sspf(float x){
  float ax = fabsf(x);
  return fmaxf(x, 0.f) + log1pf(expf(-ax)) - 0.69314718055994531f;
}

// ---------------- setup: zero cnt + transpose Wfc ----------------
__global__ void __launch_bounds__(1024) k_setup(
    const float* __restrict__ Wfc, float* __restrict__ WfcT, int* __restrict__ cnt){
  int t = blockIdx.x*1024 + threadIdx.x;
  if (t < kNodes) cnt[t] = 0;
  if (t < kNW){
    #pragma unroll
    for (int b=0;b<8;++b) WfcT[t*8+b] = Wfc[b*kNW + t];
  }
}

// ---------------- per-edge messages: 8 waves per 64-edge group ----------------
// Absorbs lin1 (h = _lin(x,W1)) and the bucket-slot atomic.
// Wave q owns w-slice q; WfcT/W1 indices wave-uniform -> s_load path.
// LDS pad 41: stride mod 32 = 9, coprime -> 2 lanes/bank = free.
__global__ void __launch_bounds__(512) k_edge(
    const float* __restrict__ er, const float* __restrict__ esh,
    const int* __restrict__ esrc, const int* __restrict__ edst,
    const float* __restrict__ x, const float* __restrict__ W1s,
    const float* __restrict__ W1v, const float* __restrict__ WfcT,
    float* __restrict__ msg, int* __restrict__ cnt){
  __shared__ float sh_x[64][41];
  __shared__ float sh_h[64][41];
  __shared__ int   smp[64];
  int t = threadIdx.x;
  int lane = t & 63;
  int q = __builtin_amdgcn_readfirstlane(t >> 6);   // 0..7, wave-uniform
  int e0 = blockIdx.x*64;                           // exact grid: 2500*64

  // ---- wave 0: issue bucket-slot atomic early (latency hides under staging) ----
  int myoff = 0;
  if (q == 0){
    int dst = edst[e0 + lane];
    int pos = atomicAdd(&cnt[dst], 1);
    myoff = (dst*kCap + pos)*kDim;
  }
  // ---- cooperative stage of x[src]: 64 edges x 10 float4 ----
  for (int idx = t; idx < 640; idx += 512){
    int el = idx/10, c4 = idx - el*10;
    int src = esrc[e0 + el];
    const float4 v = *(const float4*)(x + (size_t)src*kDim + c4*4);
    float* d = &sh_x[el][c4*4];
    d[0]=v.x; d[1]=v.y; d[2]=v.z; d[3]=v.w;
  }
  if (q == 0) smp[lane] = myoff;
  __syncthreads();

  // ---- inline lin1: wave q computes h-column c = q + 8k (uniform) for el=lane ----
  {
    #pragma unroll
    for (int k=0;k<5;++k){
      const int c = q + 8*k;
      float o;
      if (c < 16){
        float acc=0.f;
        #pragma unroll
        for (int u=0;u<16;++u) acc += sh_x[lane][u]*W1s[u*16+c];
        o = acc*0.25f;                        // 1/sqrt(16)
      } else {
        int j = c-16; int v = j/3, i = j-3*v; // wave-uniform
        float acc=0.f;
        #pragma unroll
        for (int u=0;u<8;++u) acc += sh_x[lane][16+u*3+i]*W1v[u*8+v];
        o = acc*0.35355339059327373f;         // 1/sqrt(8)
      }
      sh_h[lane][c] = o;
    }
  }
  __syncthreads();

  int e = e0 + lane;
  float4 ra = *(const float4*)(er + (size_t)e*8);
  float4 rb = *(const float4*)(er + (size_t)e*8 + 4);
  const float r0=ra.x,r1=ra.y,r2=ra.z,r3=ra.w,r4=rb.x,r5=rb.y,r6=rb.z,r7=rb.w;
  float4 s4 = *(const float4*)(esh + (size_t)e*4);
  const float* hl = sh_h[lane];
  float* mp = msg + smp[lane];

#define DOT8(p) ((p)[0]*r0+(p)[1]*r1+(p)[2]*r2+(p)[3]*r3+(p)[4]*r4+(p)[5]*r5+(p)[6]*r6+(p)[7]*r7)

  const int w0 = q*2;     // scalar w-range [w0, w0+2); vector w index = q
  float t00a=0.f, t00b=0.f, t11a=0.f, t11b=0.f;
  float t01=0.f, tx=0.f, ty=0.f, tz=0.f;

  #pragma unroll
  for (int u=0;u<16;++u){
    float xu = hl[u];
    const float* p0 = WfcT + (size_t)(u*16 + w0)*8;
    t00a += xu*DOT8(p0);
    t00b += xu*DOT8(p0 + 8);
    const float* p1 = WfcT + (size_t)(256 + u*8 + q)*8;
    t01 += xu*DOT8(p1);
  }
  #pragma unroll
  for (int u=0;u<8;++u){
    float v0=hl[16+u*3], v1=hl[16+u*3+1], v2=hl[16+u*3+2];
    float au = v0*s4.y + v1*s4.z + v2*s4.w;
    const float* p3 = WfcT + (size_t)(448 + u*16 + w0)*8;
    t11a += au*DOT8(p3);
    t11b += au*DOT8(p3 + 8);
    const float* p2 = WfcT + (size_t)(384 + u*8 + q)*8;
    float a = DOT8(p2);
    tx += v0*a; ty += v1*a; tz += v2*a;
  }
#undef DOT8

  constexpr float cs00 = 0.0625f;               // inv2/(sqrt8*4)
  constexpr float cs11 = 0.05103103630798288f;  // 1/sqrt(384)
  constexpr float cv01 = 0.0625f;
  constexpr float cv10 = 0.08838834764831845f;  // inv2/8

  // scalar pair at mp + 2q (8B-aligned)
  *(float2*)(mp + w0) = make_float2(s4.x*t00a*cs00 + t11a*cs11,
                                    s4.x*t00b*cs00 + t11b*cs11);
  // vector triple at mp + 16 + 3q
  float va = t01*cv01, sc0 = s4.x*cv10;
  float* vp = mp + 16 + q*3;
  vp[0] = s4.y*va + tx*sc0;
  vp[1] = s4.z*va + ty*sc0;
  vp[2] = s4.w*va + tz*sc0;
}

// ---------------- fused gather + linear2 + gate + residual, LDS-staged weights ----------------
// 960 threads = 24 nodes; gather mapping t -> (node, float4-chunk, k-phase) = 24*10*4.
__global__ void __launch_bounds__(960) k_node(
    const float* __restrict__ x, const float* __restrict__ msg,
    const int* __restrict__ cnt,
    const float* __restrict__ W2s, const float* __restrict__ W2v,
    const float* __restrict__ R00, const float* __restrict__ R01,
    const float* __restrict__ R10, const float* __restrict__ R11,
    float* __restrict__ out){
  __shared__ float sR00[4096], sR01[1024], sR10[1024], sR11[1024];
  __shared__ float sW2s[256], sW2v[64];
  __shared__ float sx[kNB][40], sa[kNB][40];
  __shared__ float4 sred[kNB][4][10];
  int t = threadIdx.x;
  // ---- stage weights (float4, coalesced) ----
  for (int i=t; i<1024; i+=960) ((float4*)sR00)[i] = ((const float4*)R00)[i];
  if (t < 256){
    ((float4*)sR01)[t] = ((const float4*)R01)[t];
    ((float4*)sR10)[t] = ((const float4*)R10)[t];
    ((float4*)sR11)[t] = ((const float4*)R11)[t];
  }
  if (t >= 256 && t < 320) ((float4*)sW2s)[t-256] = ((const float4*)W2s)[t-256];
  if (t >= 320 && t < 336) ((float4*)sW2v)[t-320] = ((const float4*)W2v)[t-320];
  // ---- gather from bucket: vectorized, 4 k-phases ----
  int nb = blockIdx.x*kNB;
  {
    int ns = t/40; int rem = t - ns*40; int kq = rem/10; int c4 = rem - kq*10;
    int n = nb + ns;
    float4 acc = make_float4(0.f,0.f,0.f,0.f);
    if (n < kNodes){
      int deg = cnt[n];
      const float* bp = msg + (size_t)n*kCap*kDim + c4*4;
      for (int k=kq; k<deg; k+=4){
        const float4 v = *(const float4*)(bp + (size_t)k*kDim);
        acc.x+=v.x; acc.y+=v.y; acc.z+=v.z; acc.w+=v.w;
      }
    }
    sred[ns][kq][c4] = acc;
  }
  __syncthreads();
  if (t < kNB*10){
    int ns = t/10, c4 = t - ns*10, n = nb+ns;
    float4 a0 = sred[ns][0][c4], a1 = sred[ns][1][c4];
    float4 a2 = sred[ns][2][c4], a3 = sred[ns][3][c4];
    sa[ns][c4*4+0] = (a0.x+a1.x+a2.x+a3.x)*0.25f;   // fold 1/deg = 1/4
    sa[ns][c4*4+1] = (a0.y+a1.y+a2.y+a3.y)*0.25f;
    sa[ns][c4*4+2] = (a0.z+a1.z+a2.z+a3.z)*0.25f;
    sa[ns][c4*4+3] = (a0.w+a1.w+a2.w+a3.w)*0.25f;
    float4 xv = (n < kNodes) ? *(const float4*)(x + (size_t)n*kDim + c4*4)
                             : make_float4(0.f,0.f,0.f,0.f);
    sx[ns][c4*4+0]=xv.x; sx[ns][c4*4+1]=xv.y; sx[ns][c4*4+2]=xv.z; sx[ns][c4*4+3]=xv.w;
  }
  __syncthreads();
  if (t < kNB*16){
    // ---- scalar outputs ----
    int ns = t>>4, w = t&15, n = nb+ns;
    const float* ap = sa[ns];
    const float* xp = sx[ns];
    float hsum = 0.f;
    #pragma unroll
    for (int u=0;u<16;++u) hsum += ap[u]*sW2s[u*16+w];
    hsum *= 0.25f;                 // 1/sqrt(16)
    float nrm = sqrtf(hsum*hsum + 1e-16f);
    float val = hsum/nrm*sspf(nrm);
    float xs[16];
    #pragma unroll
    for (int v=0;v<16;++v) xs[v] = xp[v];
    float r0 = 0.f;
    #pragma unroll
    for (int u=0;u<16;++u){
      float tacc = 0.f;
      #pragma unroll
      for (int v=0;v<16;++v) tacc += xs[v]*sR00[(u*16+v)*16+w];
      r0 += xs[u]*tacc;
    }
    float xv[24];
    #pragma unroll
    for (int c2=0;c2<24;++c2) xv[c2] = xp[16+c2];
    float r1 = 0.f;
    #pragma unroll
    for (int u=0;u<8;++u){
      #pragma unroll
      for (int v=0;v<8;++v){
        float dot = xv[u*3]*xv[v*3] + xv[u*3+1]*xv[v*3+1] + xv[u*3+2]*xv[v*3+2];
        r1 += dot*sR11[(u*8+v)*16+w];
      }
    }
    if (n < kNodes)
      out[(size_t)n*kDim + w] = val + 0.04419417382415922f*r0 + 0.05103103630798288f*r1;
  } else if (t < kNB*16 + kNB*24) {
    // ---- vector outputs ----
    int t2 = t - kNB*16;
    int ns = t2/24, cc = t2 - ns*24, w = cc/3, i = cc - w*3, n = nb+ns;
    const float* ap = sa[ns] + 16;
    const float* xp = sx[ns];
    float h0=0.f,h1=0.f,h2=0.f;
    #pragma unroll
    for (int u=0;u<8;++u){
      float wv = sW2v[u*8+w];
      h0 += ap[u*3+0]*wv; h1 += ap[u*3+1]*wv; h2 += ap[u*3+2]*wv;
    }
    const float sc = 0.35355339059327373f;   // 1/sqrt(8)
    h0*=sc; h1*=sc; h2*=sc;
    float nv = sqrtf(h0*h0+h1*h1+h2*h2 + 1e-16f);
    float hi = (i==0)?h0:((i==1)?h1:h2);
    float val = hi/nv*sspf(nv);
    float xs[16];
    #pragma unroll
    for (int v=0;v<16;++v) xs[v] = xp[v];
    float xvi[8];
    #pragma unroll
    for (int v=0;v<8;++v) xvi[v] = xp[16+v*3+i];
    float racc = 0.f;
    #pragma unroll
    for (int u=0;u<16;++u){
      float tacc=0.f;
      #pragma unroll
      for (int v=0;v<8;++v) tacc += xvi[v]*sR01[(u*8+v)*8+w];
      racc += xs[u]*tacc;
    }
    #pragma unroll
    for (int u=0;u<8;++u){
      float tacc=0.f;
      #pragma unroll
      for (int v=0;v<16;++v) tacc += xs[v]*sR10[(u*16+v)*8+w];
      racc += xvi[u]*tacc;
    }
    if (n < kNodes)
      out[(size_t)n*kDim + 16 + cc] = val + 0.0625f*racc;   // inv2/sqrt(128)
  }
}

extern "C" void kernel_launch(void* const* d_in, const int* in_sizes, int n_in,
                              void* d_out, int out_size, void* d_ws, size_t ws_size,
                              hipStream_t stream){
  const float* x   = (const float*)d_in[0];
  const float* er  = (const float*)d_in[1];
  const float* esh = (const float*)d_in[2];
  const int*   esrc= (const int*)d_in[3];
  const int*   edst= (const int*)d_in[4];
  const float* W1s = (const float*)d_in[6];
  const float* W1v = (const float*)d_in[7];
  const float* Wfc = (const float*)d_in[8];
  const float* W2s = (const float*)d_in[9];
  const float* W2v = (const float*)d_in[10];
  const float* R00 = (const float*)d_in[11];
  const float* R01 = (const float*)d_in[12];
  const float* R10 = (const float*)d_in[13];
  const float* R11 = (const float*)d_in[14];
  float* out = (float*)d_out;

  // ws layout (16B-aligned blocks)
  char* wsb = (char*)d_ws;
  float* msg  = (float*)wsb;                                     // 10000*96*40 f (153.6 MB)
  float* WfcT = msg + (size_t)kNodes*kCap*kDim;                  // 4,608 f
  int*   cnt  = (int*)(WfcT + (size_t)kNW*8);                    // 10,000

  k_setup<<<10, 1024, 0, stream>>>(Wfc, WfcT, cnt);
  k_edge<<<kEdges/64, 512, 0, stream>>>(er, esh, esrc, edst, x, W1s, W1v, WfcT, msg, cnt);
  k_node<<<(kNodes+kNB-1)/kNB, 960, 0, stream>>>(x, msg, cnt, W2s, W2v, R00, R01, R10, R11, out);
}